// Round 7
// baseline (129.037 us; speedup 1.0000x reference)
//
#include <hip/hip_runtime.h>
#include <hip/hip_bf16.h>

// out[8192,64] = L[8192,8192] (fp32) @ M[8192,64] (fp32)
// K1 (build_btf): BTF = B bf16 in MFMA-fragment order (8 KB per 64-k step).
// K2 (crowd_mm): BARRIER-FREE. Each wave fully independent:
//   A: wave-private LDS regions via global_load_lds(16B), XOR-swizzled
//      (pre-swizzled source), double-buffered 2x16KB per block.
//   B: fragment-direct contiguous 1KB global loads from L2-resident BTF,
//      double-buffered in named reg arrays (64 VGPR).
//   Per-wave counted s_waitcnt vmcnt(12) (= one step's 12 loads): everything
//   issued >=2 steps ago is complete. vmcnt(0) only at the final step.
//   BM=64, 256 thr, 32KB LDS -> 4 blocks/CU, grid 128x8 = exactly 4/CU.
// Split-K=8, fp32 atomics onto memset-zeroed out.

#define NPED 8192
#define HID  64
#define BM   64
#define BK   64
#define KSPLIT 8
#define KRANGE (NPED / KSPLIT)   // 1024
#define NSTEPS (KRANGE / BK)     // 16

typedef __bf16 bf16x8 __attribute__((ext_vector_type(8)));
typedef float  f32x4  __attribute__((ext_vector_type(4)));
typedef unsigned short u16;
typedef u16 u16x8 __attribute__((ext_vector_type(8)));

__device__ __forceinline__ bf16x8 cvt8(float4 lo, float4 hi) {
    bf16x8 r;
    r[0] = (__bf16)lo.x; r[1] = (__bf16)lo.y; r[2] = (__bf16)lo.z; r[3] = (__bf16)lo.w;
    r[4] = (__bf16)hi.x; r[5] = (__bf16)hi.y; r[6] = (__bf16)hi.z; r[7] = (__bf16)hi.w;
    return r;
}

__device__ __forceinline__ void gl_lds16(const void* g, void* l) {
    __builtin_amdgcn_global_load_lds(
        (const __attribute__((address_space(1))) void*)g,
        (__attribute__((address_space(3))) void*)l, 16, 0, 0);
}

// ---- K1: B [8192,64] fp32 -> BTF fragment-ordered bf16 (1 MB) ----
// BTF[((S*8+f)*64 + l)*8 + j] = bf16(B[S*64 + (f>>2)*32 + (l>>4)*8 + j][(f&3)*16 + (l&15)])
__global__ __launch_bounds__(256)
void build_btf(const float* __restrict__ B, u16* __restrict__ BTF) {
    __shared__ u16 t[64][72];
    const int tid = threadIdx.x;
    const int S   = blockIdx.x;
    const int kb  = S * 64;
    {
        const int r  = tid >> 2;
        const int c0 = (tid & 3) * 16;
        const float* p = B + (long)(kb + r) * HID + c0;
        #pragma unroll
        for (int j = 0; j < 16; j += 4) {
            float4 v = *(const float4*)(p + j);
            __bf16 b0 = (__bf16)v.x, b1 = (__bf16)v.y, b2 = (__bf16)v.z, b3 = (__bf16)v.w;
            t[c0 + j + 0][r] = __builtin_bit_cast(u16, b0);
            t[c0 + j + 1][r] = __builtin_bit_cast(u16, b1);
            t[c0 + j + 2][r] = __builtin_bit_cast(u16, b2);
            t[c0 + j + 3][r] = __builtin_bit_cast(u16, b3);
        }
    }
    __syncthreads();
    {
        const int f  = tid >> 5;
        const int s  = f >> 2, tt = f & 3;
        const int l0 = (tid & 31) * 2;
        u16* q = BTF + ((long)(S * 8 + f) * 64 + l0) * 8;
        #pragma unroll
        for (int i = 0; i < 2; ++i) {
            const int l  = l0 + i;
            const int h  = tt * 16 + (l & 15);
            const int kl = s * 32 + (l >> 4) * 8;
            u16x8 v;
            #pragma unroll
            for (int j = 0; j < 8; ++j) v[j] = t[h][kl + j];
            *(u16x8*)(q + i * 8) = v;
        }
    }
}

// ---- K2: barrier-free streaming MFMA ----
__global__ __launch_bounds__(256, 4)
void crowd_mm(const float* __restrict__ A, const u16* __restrict__ BTF,
              float* __restrict__ out)
{
    __shared__ float Aa[BM * BK];   // 16 KB, wave-private quarters, XOR-swizzled
    __shared__ float Ab[BM * BK];   // 16 KB

    const int tid  = threadIdx.x;
    const int lane = tid & 63;
    const int w    = tid >> 6;       // wave 0..3, owns rows w*16..+15
    const int rb   = blockIdx.x;     // 0..127
    const int ks   = blockIdx.y;     // 0..7

    const int l15  = lane & 15;
    const int l4   = lane >> 4;
    const int cb16 = l15 * 16;

    const char* Abase = (const char*)(A + (long)(rb * BM) * NPED + (long)ks * KRANGE);
    // B: step stride 4096 u16 (8 KB); fragment f at +f*512 u16; lane at +lane*8
    const u16* Bp = BTF + (long)(ks * NSTEPS) * 4096 + lane * 8;

    u16x8 B0[8], B1[8];              // named double buffers, constant-indexed
    f32x4 acc[4] = {};

#define LOADB(DST, STEP) do {                                                    \
    _Pragma("unroll")                                                            \
    for (int f = 0; f < 8; ++f)                                                  \
        DST[f] = *(const u16x8*)(Bp + (STEP) * 4096 + f * 512);                  \
} while (0)

#define STAGE(LBUF, STEP) do {                                                   \
    _Pragma("unroll")                                                            \
    for (int I = 0; I < 4; ++I) {                                                \
        const int row4 = w * 16 + I * 4 + l4;                                    \
        const char* src = Abase + (long)row4 * (NPED * 4)                        \
                        + (STEP) * 256 + (cb16 ^ ((row4 & 7) << 4));             \
        gl_lds16(src, (char*)(LBUF) + (w * 4 + I) * 1024);                       \
    }                                                                            \
} while (0)

    // Per-wave step: wait "everything >=2 steps old done", ds_read own A rows,
    // re-stage this LDS buffer for step+2, MFMA, reload this B buffer for step+2.
#define STEPBODY(ALDS, BREG, STEP, VM) do {                                      \
    asm volatile("s_waitcnt vmcnt(" #VM ")" ::: "memory");                       \
    __builtin_amdgcn_sched_barrier(0);                                           \
    const char* ab_ = (const char*)(ALDS);                                       \
    const int row_ = w * 16 + l15;                                               \
    const int sw_  = (row_ & 7) << 4;                                            \
    const int rB_  = row_ * 256;                                                 \
    float4 fa0 = *(const float4*)(ab_ + rB_ + ((l4 * 32)            ^ sw_));     \
    float4 fa1 = *(const float4*)(ab_ + rB_ + ((l4 * 32 + 16)       ^ sw_));     \
    float4 fa2 = *(const float4*)(ab_ + rB_ + ((128 + l4 * 32)      ^ sw_));     \
    float4 fa3 = *(const float4*)(ab_ + rB_ + ((128 + l4 * 32 + 16) ^ sw_));     \
    asm volatile("s_waitcnt lgkmcnt(0)" ::: "memory");                           \
    __builtin_amdgcn_sched_barrier(0);                                           \
    if ((STEP) + 2 < NSTEPS) STAGE(ALDS, (STEP) + 2);                            \
    bf16x8 af0 = cvt8(fa0, fa1);                                                 \
    bf16x8 af1 = cvt8(fa2, fa3);                                                 \
    acc[0] = __builtin_amdgcn_mfma_f32_16x16x32_bf16(                            \
        af0, __builtin_bit_cast(bf16x8, BREG[0]), acc[0], 0, 0, 0);              \
    acc[1] = __builtin_amdgcn_mfma_f32_16x16x32_bf16(                            \
        af0, __builtin_bit_cast(bf16x8, BREG[1]), acc[1], 0, 0, 0);              \
    acc[2] = __builtin_amdgcn_mfma_f32_16x16x32_bf16(                            \
        af0, __builtin_bit_cast(bf16x8, BREG[2]), acc[2], 0, 0, 0);              \
    acc[3] = __builtin_amdgcn_mfma_f32_16x16x32_bf16(                            \
        af0, __builtin_bit_cast(bf16x8, BREG[3]), acc[3], 0, 0, 0);              \
    acc[0] = __builtin_amdgcn_mfma_f32_16x16x32_bf16(                            \
        af1, __builtin_bit_cast(bf16x8, BREG[4]), acc[0], 0, 0, 0);              \
    acc[1] = __builtin_amdgcn_mfma_f32_16x16x32_bf16(                            \
        af1, __builtin_bit_cast(bf16x8, BREG[5]), acc[1], 0, 0, 0);              \
    acc[2] = __builtin_amdgcn_mfma_f32_16x16x32_bf16(                            \
        af1, __builtin_bit_cast(bf16x8, BREG[6]), acc[2], 0, 0, 0);              \
    acc[3] = __builtin_amdgcn_mfma_f32_16x16x32_bf16(                            \
        af1, __builtin_bit_cast(bf16x8, BREG[7]), acc[3], 0, 0, 0);              \
    if ((STEP) + 2 < NSTEPS) LOADB(BREG, (STEP) + 2);                            \
} while (0)

    // Prologue: 2 steps in flight per wave (24 vmem outstanding)
    LOADB(B0, 0); STAGE(Aa, 0);
    LOADB(B1, 1); STAGE(Ab, 1);

    #pragma unroll
    for (int it = 0; it < 7; ++it) {
        STEPBODY(Aa, B0, 2 * it,     12);
        STEPBODY(Ab, B1, 2 * it + 1, 12);
    }
    STEPBODY(Aa, B0, 14, 12);        // step-15 loads stay in flight
    STEPBODY(Ab, B1, 15, 0);         // final drain

    // Epilogue: C/D layout col = lane&15, row = (lane>>4)*4 + reg
    #pragma unroll
    for (int t = 0; t < 4; ++t) {
        #pragma unroll
        for (int r = 0; r < 4; ++r) {
            int row = rb * BM + w * 16 + l4 * 4 + r;
            int col = t * 16 + l15;
            atomicAdd(&out[row * HID + col], acc[t][r]);
        }
    }
#undef LOADB
#undef STAGE
#undef STEPBODY
}

extern "C" void kernel_launch(void* const* d_in, const int* in_sizes, int n_in,
                              void* d_out, int out_size, void* d_ws, size_t ws_size,
                              hipStream_t stream) {
    const float* A = (const float*)d_in[0];   // location_data [8192, 8192]
    const float* B = (const float*)d_in[1];   // motion_data   [8192, 64]
    float* out = (float*)d_out;               // [8192, 64]
    u16* BTF = (u16*)d_ws;                    // 1 MB fragment-ordered B

    hipMemsetAsync(d_out, 0, (size_t)out_size * sizeof(float), stream);
    build_btf<<<dim3(NPED / 64), 256, 0, stream>>>(B, BTF);

    dim3 grid(NPED / BM, KSPLIT);
    crowd_mm<<<grid, 256, 0, stream>>>(A, BTF, out);
}

// Round 9
// 62.464 us; speedup vs baseline: 2.0658x; 2.0658x over previous
//
#include <hip/hip_runtime.h>
#include <hip/hip_bf16.h>

// out[8192,64] = L[8192,8192] (fp32) @ M[8192,64] (fp32)
// R9 = R8 with the STAGE_B fragment-offset bug fixed (+ w*512).
// K1 (build_btf): BTF = B bf16 in MFMA-fragment order (8 KB per 64-k step).
// K2: BM=128, 512 thr (8 waves), LDS 144KB -> 1 block/CU.
//     A: fp32 via global_load_lds(16B), pair-buffered 2x64KB, XOR-swizzled
//        (pre-swizzled per-lane global source, swizzled ds_read). Wave-private.
//     B: fragment-ordered 1KB gl_lds per wave/step, dbuf 2x8KB (bar2-protected).
//     Staging leads: pair q halves at steps 2q-3/2q-2; B(s+2) at step s.
//     Uniform s_waitcnt vmcnt(5) (tail: 1, 0). Two barriers per 64-k step.
// Split-K=8, fp32 atomics onto memset-zeroed out.

#define NPED 8192
#define HID  64
#define BM   128
#define KSPLIT 8
#define KRANGE (NPED / KSPLIT)   // 1024
#define NSTEPS (KRANGE / 64)     // 16 (64-k compute steps; 8 A-pairs)

typedef __bf16 bf16x8 __attribute__((ext_vector_type(8)));
typedef float  f32x4  __attribute__((ext_vector_type(4)));
typedef unsigned short u16;
typedef u16 u16x8 __attribute__((ext_vector_type(8)));

__device__ __forceinline__ bf16x8 cvt8(float4 lo, float4 hi) {
    bf16x8 r;
    r[0] = (__bf16)lo.x; r[1] = (__bf16)lo.y; r[2] = (__bf16)lo.z; r[3] = (__bf16)lo.w;
    r[4] = (__bf16)hi.x; r[5] = (__bf16)hi.y; r[6] = (__bf16)hi.z; r[7] = (__bf16)hi.w;
    return r;
}

__device__ __forceinline__ void gl_lds16(const void* g, void* l) {
    __builtin_amdgcn_global_load_lds(
        (const __attribute__((address_space(1))) void*)g,
        (__attribute__((address_space(3))) void*)l, 16, 0, 0);
}

// ---- K1: B [8192,64] fp32 -> BTF fragment-ordered bf16 (1 MB) ----
// BTF[((S*8+f)*64 + l)*8 + j] = bf16(B[S*64 + (f>>2)*32 + (l>>4)*8 + j][(f&3)*16 + (l&15)])
__global__ __launch_bounds__(256)
void build_btf(const float* __restrict__ B, u16* __restrict__ BTF) {
    __shared__ u16 t[64][72];
    const int tid = threadIdx.x;
    const int S   = blockIdx.x;
    const int kb  = S * 64;
    {
        const int r  = tid >> 2;
        const int c0 = (tid & 3) * 16;
        const float* p = B + (long)(kb + r) * HID + c0;
        #pragma unroll
        for (int j = 0; j < 16; j += 4) {
            float4 v = *(const float4*)(p + j);
            __bf16 b0 = (__bf16)v.x, b1 = (__bf16)v.y, b2 = (__bf16)v.z, b3 = (__bf16)v.w;
            t[c0 + j + 0][r] = __builtin_bit_cast(u16, b0);
            t[c0 + j + 1][r] = __builtin_bit_cast(u16, b1);
            t[c0 + j + 2][r] = __builtin_bit_cast(u16, b2);
            t[c0 + j + 3][r] = __builtin_bit_cast(u16, b3);
        }
    }
    __syncthreads();
    {
        const int f  = tid >> 5;
        const int s  = f >> 2, tt = f & 3;
        const int l0 = (tid & 31) * 2;
        u16* q = BTF + ((long)(S * 8 + f) * 64 + l0) * 8;
        #pragma unroll
        for (int i = 0; i < 2; ++i) {
            const int l  = l0 + i;
            const int h  = tt * 16 + (l & 15);
            const int kl = s * 32 + (l >> 4) * 8;
            u16x8 v;
            #pragma unroll
            for (int j = 0; j < 8; ++j) v[j] = t[h][kl + j];
            *(u16x8*)(q + i * 8) = v;
        }
    }
}

// ---- K2: streaming MFMA, 512B-per-row A bursts ----
__global__ __launch_bounds__(512, 2)
void crowd_mm(const float* __restrict__ A, const u16* __restrict__ BTF,
              float* __restrict__ out)
{
    __shared__ float Aa[BM * 128];   // 64 KB: A pair-tile (even pairs), swizzled
    __shared__ float Ab[BM * 128];   // 64 KB: odd pairs
    __shared__ u16   Ba[4096];       // 8 KB: B step tile (even steps)
    __shared__ u16   Bb[4096];       // 8 KB

    const int tid  = threadIdx.x;
    const int lane = tid & 63;
    const int w    = tid >> 6;       // wave 0..7, owns rows w*16..+15
    const int rb   = blockIdx.x;     // 0..63
    const int ks   = blockIdx.y;     // 0..7

    const int l15  = lane & 15;
    const int l4   = lane >> 4;

    const char* Abase = (const char*)(A + (long)(rb * BM) * NPED + (long)ks * KRANGE);
    const u16*  Bbase = BTF + (long)(ks * NSTEPS) * 4096 + lane * 8;

    f32x4 acc[4] = {};

    // Stage rows-half H (0/1) of A-pair Q into LBUF: 4 gl_lds, each 2 rows x 512B.
    // LDS[row][x] = A[row][x ^ ((row&7)<<4)], x = byte col in [0,512).
#define STAGE_A(LBUF, Q, H) do {                                                 \
    _Pragma("unroll")                                                            \
    for (int I = 0; I < 4; ++I) {                                                \
        const int rr = w * 16 + (H) * 8 + I * 2 + (lane >> 5);                   \
        const int cs = ((lane & 31) * 16) ^ ((rr & 7) << 4);                     \
        const char* src = Abase + (long)rr * (NPED * 4) + (Q) * 512 + cs;        \
        gl_lds16(src, (char*)(LBUF) + (w * 16 + (H) * 8 + I * 2) * 512);         \
    }                                                                            \
} while (0)

    // Wave w stages its own fragment chunk f=w (1 KB contiguous) of step STEP.
#define STAGE_B(BLDS, STEP) \
    gl_lds16(Bbase + (long)(STEP) * 4096 + w * 512, (char*)(BLDS) + w * 1024)

    // One 64-k compute step s: read A sub-tile (s&1) of pair buffer, B tile,
    // then (post-bar2) stage pair ((s+3)>>1) rows-half ((s+3)&1) and B(s+2).
#define STEPM(S, VM) do {                                                        \
    asm volatile("s_waitcnt vmcnt(" #VM ")" ::: "memory");                       \
    __builtin_amdgcn_s_barrier();                                                \
    const char* ab_ = (const char*)((((S) >> 1) & 1) ? Ab : Aa);                 \
    const char* bb_ = (const char*)(((S) & 1) ? Bb : Ba);                        \
    const int row_ = w * 16 + l15;                                               \
    const int sw_  = (row_ & 7) << 4;                                            \
    const int rB_  = row_ * 512;                                                 \
    const int sub_ = ((S) & 1) * 256;                                            \
    float4 fa0 = *(const float4*)(ab_ + rB_ + ((sub_ + l4 * 32)       ^ sw_));   \
    float4 fa1 = *(const float4*)(ab_ + rB_ + ((sub_ + l4 * 32 + 16)  ^ sw_));   \
    float4 fa2 = *(const float4*)(ab_ + rB_ + ((sub_ + 128 + l4 * 32) ^ sw_));   \
    float4 fa3 = *(const float4*)(ab_ + rB_ + ((sub_ + 128 + l4 * 32 + 16) ^ sw_)); \
    bf16x8 bf0 = *(const bf16x8*)(bb_ + 0 * 1024 + lane * 16);                   \
    bf16x8 bf1 = *(const bf16x8*)(bb_ + 1 * 1024 + lane * 16);                   \
    bf16x8 bf2 = *(const bf16x8*)(bb_ + 2 * 1024 + lane * 16);                   \
    bf16x8 bf3 = *(const bf16x8*)(bb_ + 3 * 1024 + lane * 16);                   \
    bf16x8 bf4 = *(const bf16x8*)(bb_ + 4 * 1024 + lane * 16);                   \
    bf16x8 bf5 = *(const bf16x8*)(bb_ + 5 * 1024 + lane * 16);                   \
    bf16x8 bf6 = *(const bf16x8*)(bb_ + 6 * 1024 + lane * 16);                   \
    bf16x8 bf7 = *(const bf16x8*)(bb_ + 7 * 1024 + lane * 16);                   \
    asm volatile("s_waitcnt lgkmcnt(0)" ::: "memory");                           \
    __builtin_amdgcn_s_barrier();                                                \
    if ((S) <= 12) {                                                             \
        const int q_ = ((S) + 3) >> 1, h_ = ((S) + 3) & 1;                       \
        if (q_ & 1) STAGE_A(Ab, q_, h_); else STAGE_A(Aa, q_, h_);               \
    }                                                                            \
    if ((S) <= 13) { if (((S) & 1)) STAGE_B(Bb, (S) + 2); else STAGE_B(Ba, (S) + 2); } \
    bf16x8 af0 = cvt8(fa0, fa1);                                                 \
    bf16x8 af1 = cvt8(fa2, fa3);                                                 \
    acc[0] = __builtin_amdgcn_mfma_f32_16x16x32_bf16(af0, bf0, acc[0], 0, 0, 0); \
    acc[1] = __builtin_amdgcn_mfma_f32_16x16x32_bf16(af0, bf1, acc[1], 0, 0, 0); \
    acc[2] = __builtin_amdgcn_mfma_f32_16x16x32_bf16(af0, bf2, acc[2], 0, 0, 0); \
    acc[3] = __builtin_amdgcn_mfma_f32_16x16x32_bf16(af0, bf3, acc[3], 0, 0, 0); \
    acc[0] = __builtin_amdgcn_mfma_f32_16x16x32_bf16(af1, bf4, acc[0], 0, 0, 0); \
    acc[1] = __builtin_amdgcn_mfma_f32_16x16x32_bf16(af1, bf5, acc[1], 0, 0, 0); \
    acc[2] = __builtin_amdgcn_mfma_f32_16x16x32_bf16(af1, bf6, acc[2], 0, 0, 0); \
    acc[3] = __builtin_amdgcn_mfma_f32_16x16x32_bf16(af1, bf7, acc[3], 0, 0, 0); \
} while (0)

    // Prologue: [p0h0 x4, B0, p0h1 x4, p1h0 x4, B1] -> steady vmcnt(5).
    STAGE_A(Aa, 0, 0);
    STAGE_B(Ba, 0);
    STAGE_A(Aa, 0, 1);
    STAGE_A(Ab, 1, 0);
    STAGE_B(Bb, 1);

    STEPM(0, 5);  STEPM(1, 5);  STEPM(2, 5);  STEPM(3, 5);
    STEPM(4, 5);  STEPM(5, 5);  STEPM(6, 5);  STEPM(7, 5);
    STEPM(8, 5);  STEPM(9, 5);  STEPM(10, 5); STEPM(11, 5);
    STEPM(12, 5); STEPM(13, 5); STEPM(14, 1); STEPM(15, 0);

    // Epilogue: C/D layout col = lane&15, row = (lane>>4)*4 + reg
    #pragma unroll
    for (int t = 0; t < 4; ++t) {
        #pragma unroll
        for (int r = 0; r < 4; ++r) {
            int row = rb * BM + w * 16 + l4 * 4 + r;
            int col = t * 16 + l15;
            atomicAdd(&out[row * HID + col], acc[t][r]);
        }
    }
#undef STAGE_A
#undef STAGE_B
#undef STEPM
}

extern "C" void kernel_launch(void* const* d_in, const int* in_sizes, int n_in,
                              void* d_out, int out_size, void* d_ws, size_t ws_size,
                              hipStream_t stream) {
    const float* A = (const float*)d_in[0];   // location_data [8192, 8192]
    const float* B = (const float*)d_in[1];   // motion_data   [8192, 64]
    float* out = (float*)d_out;               // [8192, 64]
    u16* BTF = (u16*)d_ws;                    // 1 MB fragment-ordered B

    hipMemsetAsync(d_out, 0, (size_t)out_size * sizeof(float), stream);
    build_btf<<<dim3(NPED / 64), 256, 0, stream>>>(B, BTF);

    dim3 grid(NPED / BM, KSPLIT);
    crowd_mm<<<grid, 512, 0, stream>>>(A, BTF, out);
}